// Round 1
// baseline (563.245 us; speedup 1.0000x reference)
//
#include <hip/hip_runtime.h>

// Fused 4-layer MLP (2 -> 1024 -> 512 -> 256 -> 3), N = 262144, fp32 I/O.
// Strategy: fp16 MFMA (32x32x16), fp32 accumulate, everything fused per
// 128-row tile. All layers computed transposed: D[out_feat][batch] with
// A = weight frags ([out][in] frag-major, preprocessed into ws),
// B = activation frags ([batch][k] in a 64KB XOR-swizzled LDS slab).

typedef _Float16 f16;
typedef f16 f16x8 __attribute__((ext_vector_type(8)));
typedef f16 f16x4 __attribute__((ext_vector_type(4)));
typedef float f32x16 __attribute__((ext_vector_type(16)));

#define MFMA(a, b, c) __builtin_amdgcn_mfma_f32_32x32x16_f16((a), (b), (c), 0, 0, 0)

// ws layout in 16-byte units (f16x8):
//  W1F : [16 jt][64 ks][64 lane]            ->      0 .. 65536
//  W2F : [ 8 jt][32 ks][64 lane]            ->  65536 .. 81920
//  W3F : [16 ks][64 lane]                   ->  81920 .. 82944
//  P0F : [32 k1t][64 lane] (layer1 A frag)  ->  82944 .. 84992
//  B1F : [16 jt][64 lane]                   ->  84992 .. 86016
//  B2F : [ 8 jt][64 lane]                   ->  86016 .. 86528
#define U_W1F 0
#define U_W2F 65536
#define U_W3F 81920
#define U_P0F 82944
#define U_B1F 84992
#define U_B2F 86016
#define U_TOTAL 86528

__global__ void prep_kernel(const float* __restrict__ W0, const float* __restrict__ b0,
                            const float* __restrict__ W1, const float* __restrict__ b1,
                            const float* __restrict__ W2, const float* __restrict__ b2,
                            const float* __restrict__ W3, f16* __restrict__ ws)
{
    int u = blockIdx.x * 256 + threadIdx.x;
    if (u >= U_TOTAL) return;
    int lane = u & 63;
    int l31 = lane & 31;
    int q = lane >> 5;
    f16x8 v;
#pragma unroll
    for (int e = 0; e < 8; ++e) v[e] = (f16)0.f;

    if (u < U_W2F) {                       // W1F: W1 is [1024][512]
        int jt = u >> 12, ks = (u >> 6) & 63;
        int j = jt * 32 + l31;
        int kb = ks * 16 + q * 8;
        const float* p = W1 + (size_t)kb * 512 + j;
#pragma unroll
        for (int e = 0; e < 8; ++e) v[e] = (f16)p[(size_t)e * 512];
    } else if (u < U_W3F) {                // W2F: W2 is [512][256]
        int t = u - U_W2F;
        int jt = t >> 11, ks = (t >> 6) & 31;
        int j = jt * 32 + l31;
        int kb = ks * 16 + q * 8;
        const float* p = W2 + (size_t)kb * 256 + j;
#pragma unroll
        for (int e = 0; e < 8; ++e) v[e] = (f16)p[(size_t)e * 256];
    } else if (u < U_P0F) {                // W3F: W3 is [256][3], pad j>=3 with 0
        int t = u - U_W3F;
        int ks = t >> 6;
        int j = l31;
        int kb = ks * 16 + q * 8;
        if (j < 3) {
            const float* p = W3 + (size_t)kb * 3 + j;
#pragma unroll
            for (int e = 0; e < 8; ++e) v[e] = (f16)p[(size_t)e * 3];
        }
    } else if (u < U_B1F) {                // P0F: layer-1 A frag with hi/lo split + bias
        int t = u - U_P0F;
        int jt = t >> 6;
        int j = jt * 32 + l31;
        if (q == 0) {
            float w00 = W0[j], w01 = W0[1024 + j], bb = b0[j];
            f16 w00h = (f16)w00, w01h = (f16)w01, bh = (f16)bb;
            v[0] = w00h; v[1] = w01h; v[2] = bh;
            v[3] = w00h; v[4] = w01h;                       // pair with x_lo
            v[5] = (f16)(w00 - (float)w00h);                // w_lo * x_hi
            v[6] = (f16)(w01 - (float)w01h);
            v[7] = (f16)(bb - (float)bh);                   // bias residual * 1
        }
    } else if (u < U_B2F) {                // B1F
        int t = u - U_B1F;
        int jt = t >> 6;
        int j = jt * 32 + l31;
        if (q == 0) v[0] = (f16)b1[j];
    } else {                               // B2F
        int t = u - U_B2F;
        int jt = t >> 6;
        int j = jt * 32 + l31;
        if (q == 0) v[0] = (f16)b2[j];
    }
    ((f16x8*)ws)[u] = v;
}

// ---- LDS slab helpers. Slab rows: [m][k] f16, row stride rs bytes.
// XOR swizzle at 8-byte (2-dword) granularity: phys_dw = dw ^ ((m&15)<<1).
// Gives 2-way-max bank conflicts (free) for both b64 writes and reads.
__device__ __forceinline__ void slab_write4(unsigned char* lds, int m, int dw /*even*/,
                                            int rs, f16x4 val)
{
    int s = (m & 15) << 1;
    *(f16x4*)(lds + (size_t)m * rs + (size_t)((dw ^ s) << 2)) = val;
}

__device__ __forceinline__ f16x8 slab_read8(const unsigned char* lds, int m, int dw /*mult of 4*/,
                                            int rs)
{
    int s = (m & 15) << 1;
    f16x4 lo = *(const f16x4*)(lds + (size_t)m * rs + (size_t)((dw ^ s) << 2));
    f16x4 hi = *(const f16x4*)(lds + (size_t)m * rs + (size_t)(((dw + 2) ^ s) << 2));
    union { f16x8 v; f16x4 p[2]; } u;
    u.p[0] = lo; u.p[1] = hi;
    return u.v;
}

__global__ __launch_bounds__(256, 1)
void mlp_kernel(const float* __restrict__ X, const float* __restrict__ b3,
                const f16* __restrict__ ws, float* __restrict__ out)
{
    const f16x8* W1F = (const f16x8*)ws + U_W1F;
    const f16x8* W2F = (const f16x8*)ws + U_W2F;
    const f16x8* W3F = (const f16x8*)ws + U_W3F;
    const f16x8* P0F = (const f16x8*)ws + U_P0F;
    const f16x8* B1F = (const f16x8*)ws + U_B1F;
    const f16x8* B2F = (const f16x8*)ws + U_B2F;

    __shared__ __align__(16) unsigned char lds[65536];

    const int tid  = threadIdx.x;
    const int w    = tid >> 6;       // wave 0..3
    const int lane = tid & 63;
    const int l31  = lane & 31;
    const int q    = lane >> 5;
    const size_t rowbase = (size_t)blockIdx.x * 128;

    f32x16 zero16;
#pragma unroll
    for (int i = 0; i < 16; ++i) zero16[i] = 0.f;

    // X frags (B-operand for layer 1): {x0h,x1h,1, x0l,x1l, x0h,x1h, 1} on q==0 lanes
    f16x8 xfrag[4];
#pragma unroll
    for (int mt = 0; mt < 4; ++mt) {
        f16x8 v;
#pragma unroll
        for (int e = 0; e < 8; ++e) v[e] = (f16)0.f;
        if (q == 0) {
            float2 xv = ((const float2*)X)[rowbase + mt * 32 + l31];
            f16 x0h = (f16)xv.x, x1h = (f16)xv.y;
            v[0] = x0h; v[1] = x1h; v[2] = (f16)1.f;
            v[3] = (f16)(xv.x - (float)x0h);
            v[4] = (f16)(xv.y - (float)x1h);
            v[5] = x0h; v[6] = x1h; v[7] = (f16)1.f;
        }
        xfrag[mt] = v;
    }

    // ones frag for bias k-steps
    f16x8 ones;
#pragma unroll
    for (int e = 0; e < 8; ++e) ones[e] = (f16)0.f;
    if (q == 0) ones[0] = (f16)1.f;

    // ---- layer-2 accumulators [ji][mt], bias-initialized via MFMA
    f32x16 acc2[4][4];
#pragma unroll
    for (int ji = 0; ji < 4; ++ji) {
        f16x8 bfr = B1F[(w * 4 + ji) * 64 + lane];
        f32x16 binit = MFMA(bfr, ones, zero16);
#pragma unroll
        for (int mt = 0; mt < 4; ++mt) acc2[ji][mt] = binit;
    }

    // ---- fused layer1 + layer2, K chunked 4 x 256 through the slab (rs=512B)
    for (int c = 0; c < 4; ++c) {
        // layer 1: 8 k1-tiles per chunk, 2 per wave; D[k1][m] -> slab [m][k1]
        for (int i = w; i < 8; i += 4) {
            int k1t = c * 8 + i;
            f16x8 af = P0F[k1t * 64 + lane];
#pragma unroll
            for (int mt = 0; mt < 4; ++mt) {
                f32x16 d = MFMA(af, xfrag[mt], zero16);
                int m = mt * 32 + l31;           // D col -> batch row
                int kb = i * 32 + 4 * q;         // D row -> h1 feature (local)
#pragma unroll
                for (int t = 0; t < 4; ++t) {
                    f16x4 pk;
#pragma unroll
                    for (int r = 0; r < 4; ++r) {
                        float v = d[4 * t + r];
                        pk[r] = (f16)(v > 0.f ? v : 0.f);
                    }
                    slab_write4(lds, m, (kb + 8 * t) >> 1, 512, pk);
                }
            }
        }
        __syncthreads();
        // layer 2 partial K: 16 k-steps; A = W1F stream (global/L2), B = slab
        for (int ks = 0; ks < 16; ++ks) {
            int ksg = c * 16 + ks;
            f16x8 af[4], bf[4];
#pragma unroll
            for (int ji = 0; ji < 4; ++ji)
                af[ji] = W1F[((w * 4 + ji) * 64 + ksg) * 64 + lane];
#pragma unroll
            for (int mt = 0; mt < 4; ++mt)
                bf[mt] = slab_read8(lds, mt * 32 + l31, (ks * 16 + q * 8) >> 1, 512);
#pragma unroll
            for (int ji = 0; ji < 4; ++ji)
#pragma unroll
                for (int mt = 0; mt < 4; ++mt)
                    acc2[ji][mt] = MFMA(af[ji], bf[mt], acc2[ji][mt]);
        }
        __syncthreads();
    }

    // ---- layer 3: h2 (acc2, relu) -> slab in 4 chunks of 128 feats (rs=256B)
    f32x16 acc3[2][4];
#pragma unroll
    for (int ji = 0; ji < 2; ++ji) {
        f16x8 bfr = B2F[(w * 2 + ji) * 64 + lane];
        f32x16 binit = MFMA(bfr, ones, zero16);
#pragma unroll
        for (int mt = 0; mt < 4; ++mt) acc3[ji][mt] = binit;
    }
    for (int kc = 0; kc < 4; ++kc) {
        __syncthreads();
        if (w == kc) {  // this wave owns h2 features [kc*128, kc*128+128)
#pragma unroll
            for (int ji = 0; ji < 4; ++ji)
#pragma unroll
                for (int mt = 0; mt < 4; ++mt) {
                    int m = mt * 32 + l31;
                    int jb = ji * 32 + 4 * q;
#pragma unroll
                    for (int t = 0; t < 4; ++t) {
                        f16x4 pk;
#pragma unroll
                        for (int r = 0; r < 4; ++r) {
                            float v = acc2[ji][mt][4 * t + r];
                            pk[r] = (f16)(v > 0.f ? v : 0.f);
                        }
                        slab_write4(lds, m, (jb + 8 * t) >> 1, 256, pk);
                    }
                }
        }
        __syncthreads();
        for (int ks = 0; ks < 8; ++ks) {
            int ksg = kc * 8 + ks;
            f16x8 af[2], bf[4];
#pragma unroll
            for (int ji = 0; ji < 2; ++ji)
                af[ji] = W2F[((w * 2 + ji) * 32 + ksg) * 64 + lane];
#pragma unroll
            for (int mt = 0; mt < 4; ++mt)
                bf[mt] = slab_read8(lds, mt * 32 + l31, (ks * 16 + q * 8) >> 1, 256);
#pragma unroll
            for (int ji = 0; ji < 2; ++ji)
#pragma unroll
                for (int mt = 0; mt < 4; ++mt)
                    acc3[ji][mt] = MFMA(af[ji], bf[mt], acc3[ji][mt]);
        }
    }

    // ---- layer 4: h3 -> slab in 2 chunks of 128 feats; each wave computes its m-tile
    f32x16 acc4 = zero16;
    for (int kc = 0; kc < 2; ++kc) {
        __syncthreads();
        if ((w >> 1) == kc) {  // waves 2kc, 2kc+1 own h3 features [kc*128, +128)
#pragma unroll
            for (int ji = 0; ji < 2; ++ji)
#pragma unroll
                for (int mt = 0; mt < 4; ++mt) {
                    int m = mt * 32 + l31;
                    int jb = (w & 1) * 64 + ji * 32 + 4 * q;
#pragma unroll
                    for (int t = 0; t < 4; ++t) {
                        f16x4 pk;
#pragma unroll
                        for (int r = 0; r < 4; ++r) {
                            float v = acc3[ji][mt][4 * t + r];
                            pk[r] = (f16)(v > 0.f ? v : 0.f);
                        }
                        slab_write4(lds, m, (jb + 8 * t) >> 1, 256, pk);
                    }
                }
        }
        __syncthreads();
        int m = w * 32 + l31;
        for (int ks = 0; ks < 8; ++ks) {
            int ksg = kc * 8 + ks;
            f16x8 af = W3F[ksg * 64 + lane];
            f16x8 bf = slab_read8(lds, m, (ks * 16 + q * 8) >> 1, 256);
            acc4 = MFMA(af, bf, acc4);
        }
    }

    // D4[j3][m]: q==0 lanes hold rows 0..3 in regs 0..3; j3 = 0,1,2 valid
    if (q == 0) {
        size_t gm = rowbase + w * 32 + l31;
        out[gm * 3 + 0] = acc4[0] + b3[0];
        out[gm * 3 + 1] = acc4[1] + b3[1];
        out[gm * 3 + 2] = acc4[2] + b3[2];
    }
}

extern "C" void kernel_launch(void* const* d_in, const int* in_sizes, int n_in,
                              void* d_out, int out_size, void* d_ws, size_t ws_size,
                              hipStream_t stream)
{
    const float* X  = (const float*)d_in[0];
    const float* W0 = (const float*)d_in[1];
    const float* b0 = (const float*)d_in[2];
    const float* W1 = (const float*)d_in[3];
    const float* b1 = (const float*)d_in[4];
    const float* W2 = (const float*)d_in[5];
    const float* b2 = (const float*)d_in[6];
    const float* W3 = (const float*)d_in[7];
    const float* b3 = (const float*)d_in[8];
    f16* ws = (f16*)d_ws;

    int N = in_sizes[0] / 2;          // 262144
    int nblk = N / 128;               // 2048

    prep_kernel<<<(U_TOTAL + 255) / 256, 256, 0, stream>>>(W0, b0, W1, b1, W2, b2, W3, ws);
    mlp_kernel<<<nblk, 256, 0, stream>>>(X, b3, ws, (float*)d_out);
}